// Round 2
// baseline (1745.403 us; speedup 1.0000x reference)
//
#include <hip/hip_runtime.h>
#include <hip/hip_bf16.h>
#include <hip/hip_fp16.h>

// LSTM: B=512, T=512, I=128, H=256, gates G=4H=1024 (PyTorch i,f,g,o order).
// Chunked pipeline (T_c adaptive to ws_size):
//   per chunk c: xgemm -> xg_chunk[B][T_c][1024] (f16) ; lstm_chunk runs T_c steps.
// lstm_chunk: 256 blocks x 512 thr; w_hh f16: kt0-5 in 192 VGPRs/thread,
// kt6-7 as lane-fragments in 128KB dynamic LDS. h/c state in global ws.

typedef __attribute__((ext_vector_type(4))) float f32x4;
typedef __attribute__((ext_vector_type(8))) _Float16 f16x8;
typedef __attribute__((ext_vector_type(4))) unsigned int u32x4;

static __device__ __forceinline__ float h2f(unsigned short u) {
  return (float)__builtin_bit_cast(_Float16, u);
}
static __device__ __forceinline__ unsigned short f2h(float f) {
  return __builtin_bit_cast(unsigned short, (_Float16)f);
}
static __device__ __forceinline__ float fast_sigmoid(float x) {
  return __builtin_amdgcn_rcpf(1.0f + __builtin_amdgcn_exp2f(-1.44269504f * x));
}
static __device__ __forceinline__ float fast_tanh(float x) {
  return 1.0f - 2.0f * __builtin_amdgcn_rcpf(1.0f + __builtin_amdgcn_exp2f(2.88539008f * x));
}

// ---------------------------------------------------------------- casts/state
__global__ void cast_f32_f16(const float* __restrict__ src, unsigned short* __restrict__ dst, int n) {
  int i = (blockIdx.x * 256 + threadIdx.x) * 4;
  if (i < n) {
    f32x4 v = *(const f32x4*)(src + i);
    ushort4 pk;
    pk.x = f2h(v[0]); pk.y = f2h(v[1]); pk.z = f2h(v[2]); pk.w = f2h(v[3]);
    *(ushort4*)(dst + i) = pk;
  }
}

__global__ void state_init(const float* __restrict__ h0, const float* __restrict__ c0,
                           unsigned short* __restrict__ hst, float* __restrict__ cst) {
  int i = blockIdx.x * 256 + threadIdx.x;  // grid 512 -> 131072
  hst[i] = f2h(h0[i]);
  cst[i] = c0[i];
}

__global__ void finalize(const float* __restrict__ cst, float* __restrict__ out) {
  int i = blockIdx.x * 256 + threadIdx.x;
  out[i] = cst[i];
}

// ---------------------------------------------------------------- phase 1
// Block = 128 consecutive chunk-rows (cr = b*T_c + tl). 8 gate-chunks of 128.
__global__ __launch_bounds__(256) void xgemm(
    const float* __restrict__ x, const unsigned short* __restrict__ wih,
    const float* __restrict__ b_ih, const float* __restrict__ b_hh,
    unsigned short* __restrict__ xg, int t0, int tclog) {
  __shared__ unsigned short Ash[128 * 128];  // [m][k] f16, XOR-swizzled
  __shared__ unsigned short Bsh[128 * 128];  // [n][k] f16, swizzle via pre-swz src

  const int tid  = threadIdx.x;
  const int lane = tid & 63;
  const int wv   = tid >> 6;
  const int c16  = lane & 15;
  const int gq   = lane >> 4;
  const long m0  = (long)blockIdx.x * 128;
  const int tcm  = (1 << tclog) - 1;

  // stage A: 128 chunk-rows x 128 k, f32 -> f16, swizzled LDS
#pragma unroll
  for (int i = 0; i < 16; ++i) {
    int fidx = (i * 256 + tid) * 4;
    int row = fidx >> 7, k = fidx & 127;
    long cr = m0 + row;
    long b  = cr >> tclog;
    long tl = cr & tcm;
    f32x4 v = *(const f32x4*)(x + ((size_t)b * 512 + t0 + tl) * 128 + k);
    ushort4 pk;
    pk.x = f2h(v[0]); pk.y = f2h(v[1]); pk.z = f2h(v[2]); pk.w = f2h(v[3]);
    int byte = (row * 256 + k * 2) ^ ((row & 7) << 4);
    *(ushort4*)((char*)Ash + byte) = pk;
  }

  const int mh = (wv >> 1) * 64;
  const int nh = (wv & 1) * 64;

  for (int nc = 0; nc < 8; ++nc) {
    __syncthreads();  // protect Bsh readers of prev chunk (and A stage on iter 0)
    {
      const char* wb = (const char*)(wih + nc * 128 * 128);
#pragma unroll
      for (int i = 0; i < 8; ++i) {
        int idx16 = i * 256 + tid;
        int row = idx16 >> 4, ch = idx16 & 15;
        int srcoff = row * 256 + ((ch * 16) ^ ((row & 7) << 4));
        u32x4 v = *(const u32x4*)(wb + srcoff);
        *(u32x4*)((char*)Bsh + idx16 * 16) = v;
      }
    }
    __syncthreads();

    float bias_v[4];
#pragma unroll
    for (int nt = 0; nt < 4; ++nt) {
      int gc = nc * 128 + nh + nt * 16 + c16;
      bias_v[nt] = b_ih[gc] + b_hh[gc];
    }

    f16x8 af[4][4], bfr[4][4];
#pragma unroll
    for (int sm = 0; sm < 4; ++sm)
#pragma unroll
      for (int kt = 0; kt < 4; ++kt) {
        int m = mh + sm * 16 + c16;
        int byte = (m * 256 + (kt * 32 + gq * 8) * 2) ^ ((m & 7) << 4);
        af[sm][kt] = __builtin_bit_cast(f16x8, *(const u32x4*)((const char*)Ash + byte));
      }
#pragma unroll
    for (int nt = 0; nt < 4; ++nt)
#pragma unroll
      for (int kt = 0; kt < 4; ++kt) {
        int n = nh + nt * 16 + c16;
        int byte = (n * 256 + (kt * 32 + gq * 8) * 2) ^ ((n & 7) << 4);
        bfr[nt][kt] = __builtin_bit_cast(f16x8, *(const u32x4*)((const char*)Bsh + byte));
      }

    f32x4 acc[4][4];
#pragma unroll
    for (int sm = 0; sm < 4; ++sm)
#pragma unroll
      for (int nt = 0; nt < 4; ++nt) { f32x4 z = {0.f, 0.f, 0.f, 0.f}; acc[sm][nt] = z; }
#pragma unroll
    for (int sm = 0; sm < 4; ++sm)
#pragma unroll
      for (int nt = 0; nt < 4; ++nt)
#pragma unroll
        for (int kt = 0; kt < 4; ++kt)
          acc[sm][nt] = __builtin_amdgcn_mfma_f32_16x16x32_f16(af[sm][kt], bfr[nt][kt], acc[sm][nt], 0, 0, 0);

#pragma unroll
    for (int sm = 0; sm < 4; ++sm)
#pragma unroll
      for (int nt = 0; nt < 4; ++nt) {
        long row = m0 + mh + sm * 16 + gq * 4;  // D: col=c16, row=gq*4+r (HW-verified)
        int gcol = nc * 128 + nh + nt * 16 + c16;
#pragma unroll
        for (int r = 0; r < 4; ++r)
          xg[(size_t)(row + r) * 1024 + gcol] = f2h(acc[sm][nt][r] + bias_v[nt]);
      }
  }
}

// ---------------------------------------------------------------- phase 2
// dyn LDS: [0,131072) weight frags (kt6,7), [131072,139264) h (f16 swz),
//          [139264,147488) gates f32 [2][1028]
__global__ __launch_bounds__(512, 2) void lstm_chunk(
    const unsigned short* __restrict__ xg, const unsigned short* __restrict__ whh,
    unsigned short* __restrict__ hst, float* __restrict__ cst, int Tc) {
  extern __shared__ char smem[];
  char* wlds = smem;
  char* hs   = smem + 131072;
  float* gs  = (float*)(smem + 139264);

  const int tid  = threadIdx.x;
  const int lane = tid & 63;
  const int wv   = tid >> 6;      // 0..7
  const int c16  = lane & 15;
  const int gq   = lane >> 4;     // 0..3
  const int b0   = blockIdx.x * 2;

  // weight frags kt 0..5 -> registers (192 VGPR): B[k][n], n = wv*128+nt*16+c16
  f16x8 wf[8][6];
#pragma unroll
  for (int nt = 0; nt < 8; ++nt)
#pragma unroll
    for (int kt = 0; kt < 6; ++kt) {
      int n = wv * 128 + nt * 16 + c16;
      int kb = kt * 32 + gq * 8;
      wf[nt][kt] = __builtin_bit_cast(f16x8, *(const u32x4*)(whh + n * 256 + kb));
    }
  // weight frags kt 6,7 -> LDS lane-fragments (contiguous per wave instr)
#pragma unroll
  for (int nt = 0; nt < 8; ++nt)
#pragma unroll
    for (int ktl = 0; ktl < 2; ++ktl) {
      int n = wv * 128 + nt * 16 + c16;
      int kb = (6 + ktl) * 32 + gq * 8;
      u32x4 v = *(const u32x4*)(whh + n * 256 + kb);
      *(u32x4*)(wlds + (((wv * 8 + nt) * 2 + ktl) * 64 + lane) * 16) = v;
    }

  // h LDS init: rows 0,1 = state; rows 2..15 = 0 (M=16 tile padding)
  for (int i = tid; i < 4096; i += 512) {
    int row = i >> 8, col = i & 255;
    unsigned short v = (row < 2) ? hst[(b0 + row) * 256 + col] : (unsigned short)0;
    int byte = (row * 512 + col * 2) ^ ((row & 7) << 4);
    *(unsigned short*)(hs + byte) = v;
  }

  const int erow = tid >> 8;   // 0..1
  const int ecol = tid & 255;
  float c_reg = cst[(b0 + erow) * 256 + ecol];
  float hn = 0.f;

  const unsigned short* xgr = xg + (size_t)(b0 + erow) * Tc * 1024;

  unsigned short pxa0, pxa1, pxa2, pxa3, pxb0 = 0, pxb1 = 0, pxb2 = 0, pxb3 = 0;
  pxa0 = xgr[ecol]; pxa1 = xgr[256 + ecol]; pxa2 = xgr[512 + ecol]; pxa3 = xgr[768 + ecol];

  __syncthreads();

  for (int tt = 0; tt < Tc; ++tt) {
    {  // prefetch t+1 into the other register set
      int tl = (tt + 1 < Tc) ? tt + 1 : Tc - 1;
      const unsigned short* p = xgr + (size_t)tl * 1024 + ecol;
      if ((tt & 1) == 0) { pxb0 = p[0]; pxb1 = p[256]; pxb2 = p[512]; pxb3 = p[768]; }
      else               { pxa0 = p[0]; pxa1 = p[256]; pxa2 = p[512]; pxa3 = p[768]; }
    }

#pragma unroll
    for (int half = 0; half < 2; ++half) {
      f32x4 acc[4];
#pragma unroll
      for (int n4 = 0; n4 < 4; ++n4) { f32x4 z = {0.f, 0.f, 0.f, 0.f}; acc[n4] = z; }
#pragma unroll
      for (int kt = 0; kt < 8; ++kt) {
        int hb = (c16 * 512 + kt * 64 + gq * 16) ^ ((c16 & 7) << 4);
        f16x8 afr = __builtin_bit_cast(f16x8, *(const u32x4*)(hs + hb));
#pragma unroll
        for (int n4 = 0; n4 < 4; ++n4) {
          int nt = half * 4 + n4;
          f16x8 wb;
          if (kt < 6) wb = wf[nt][kt];
          else wb = __builtin_bit_cast(f16x8,
                 *(const u32x4*)(wlds + (((wv * 8 + nt) * 2 + (kt - 6)) * 64 + lane) * 16));
          acc[n4] = __builtin_amdgcn_mfma_f32_16x16x32_f16(afr, wb, acc[n4], 0, 0, 0);
        }
      }
      if (gq == 0) {  // D rows 0,1 live in regs 0,1 of gq==0 lanes
#pragma unroll
        for (int n4 = 0; n4 < 4; ++n4) {
          int gcol = wv * 128 + (half * 4 + n4) * 16 + c16;
          gs[gcol] = acc[n4][0];
          gs[1028 + gcol] = acc[n4][1];
        }
      }
    }
    __syncthreads();

    float xi, xf, xgv, xo;
    if ((tt & 1) == 0) { xi = h2f(pxa0); xf = h2f(pxa1); xgv = h2f(pxa2); xo = h2f(pxa3); }
    else               { xi = h2f(pxb0); xf = h2f(pxb1); xgv = h2f(pxb2); xo = h2f(pxb3); }

    float gi = gs[erow * 1028 + ecol]       + xi;
    float gf = gs[erow * 1028 + 256 + ecol] + xf;
    float gg = gs[erow * 1028 + 512 + ecol] + xgv;
    float go = gs[erow * 1028 + 768 + ecol] + xo;

    float ig = fast_sigmoid(gi);
    float fg = fast_sigmoid(gf);
    float gt = fast_tanh(gg);
    float og = fast_sigmoid(go);
    c_reg = fg * c_reg + ig * gt;
    hn = og * fast_tanh(c_reg);

    int hb = (erow * 512 + ecol * 2) ^ ((erow & 7) << 4);
    *(unsigned short*)(hs + hb) = f2h(hn);
    __syncthreads();
  }

  hst[(b0 + erow) * 256 + ecol] = f2h(hn);
  cst[(b0 + erow) * 256 + ecol] = c_reg;
}

// ---------------------------------------------------------------- launch
extern "C" void kernel_launch(void* const* d_in, const int* in_sizes, int n_in,
                              void* d_out, int out_size, void* d_ws, size_t ws_size,
                              hipStream_t stream) {
  const float* x   = (const float*)d_in[0];
  const float* h0  = (const float*)d_in[1];
  const float* c0  = (const float*)d_in[2];
  const float* wih = (const float*)d_in[3];
  const float* whh = (const float*)d_in[4];
  const float* bih = (const float*)d_in[5];
  const float* bhh = (const float*)d_in[6];
  float* out = (float*)d_out;

  // adaptive chunk length: xg chunk = 512*tc*1024 f16 = 512*tc*2048 bytes
  const size_t fixed = 262144u + 524288u + 262144u + 524288u;  // wih,whh,hst,cst
  int tc = 512;
  while (tc > 4 && (size_t)512 * tc * 2048 + fixed > ws_size) tc >>= 1;
  int tclog = 31 - __builtin_clz((unsigned)tc);

  char* ws = (char*)d_ws;
  unsigned short* xgb   = (unsigned short*)ws;
  size_t off = (size_t)512 * tc * 2048;
  unsigned short* wih_h = (unsigned short*)(ws + off);            off += 262144u;
  unsigned short* whh_h = (unsigned short*)(ws + off);            off += 524288u;
  unsigned short* hst   = (unsigned short*)(ws + off);            off += 262144u;
  float*          cst   = (float*)(ws + off);

  (void)hipFuncSetAttribute((const void*)lstm_chunk,
                            hipFuncAttributeMaxDynamicSharedMemorySize, 147488);

  cast_f32_f16<<<128, 256, 0, stream>>>(wih, wih_h, 131072);
  cast_f32_f16<<<256, 256, 0, stream>>>(whh, whh_h, 262144);
  state_init<<<512, 256, 0, stream>>>(h0, c0, hst, cst);

  int nchunks = 512 / tc;
  for (int c = 0; c < nchunks; ++c) {
    xgemm<<<4 * tc, 256, 0, stream>>>(x, wih_h, bih, bhh, xgb, c * tc, tclog);
    lstm_chunk<<<256, 512, 147488, stream>>>(xgb, whh_h, hst, cst, tc);
  }
  finalize<<<512, 256, 0, stream>>>(cst, out);
}

// Round 3
// 887.624 us; speedup vs baseline: 1.9664x; 1.9664x over previous
//
#include <hip/hip_runtime.h>
#include <hip/hip_bf16.h>
#include <hip/hip_fp16.h>

// LSTM: B=512, T=512, I=128, H=256, gates G=4H=1024 (PyTorch i,f,g,o order).
// Phase 1 (per chunk): xgemm -> xg[B][Tc][1024] f16 (includes both biases).
// Phase 2: lstm_chunk, 256 blocks x 8 waves; full w_hh as i8 in 128 VGPR/thread;
//   gates stay in registers (M-rows 0,8 = the 2 real batch rows); 1 barrier/step.

typedef __attribute__((ext_vector_type(4))) float f32x4;
typedef __attribute__((ext_vector_type(8))) _Float16 f16x8;
typedef __attribute__((ext_vector_type(4))) unsigned int u32x4;
typedef __attribute__((ext_vector_type(4))) int i32x4;

static __device__ __forceinline__ float h2f(unsigned short u) {
  return (float)__builtin_bit_cast(_Float16, u);
}
static __device__ __forceinline__ unsigned short f2h(float f) {
  return __builtin_bit_cast(unsigned short, (_Float16)f);
}
static __device__ __forceinline__ float fast_sigmoid(float x) {
  return __builtin_amdgcn_rcpf(1.0f + __builtin_amdgcn_exp2f(-1.44269504f * x));
}
static __device__ __forceinline__ float fast_tanh(float x) {
  return 1.0f - 2.0f * __builtin_amdgcn_rcpf(1.0f + __builtin_amdgcn_exp2f(2.88539008f * x));
}

// ---------------------------------------------------------------- small utils
__global__ void zero2(float* p) { if (threadIdx.x < 2) p[threadIdx.x] = 0.f; }

__global__ void absmax_red(const float* __restrict__ src, int n, float* __restrict__ out) {
  __shared__ float s[256];
  float m = 0.f;
  for (int i = blockIdx.x * 256 + threadIdx.x; i < n; i += gridDim.x * 256)
    m = fmaxf(m, fabsf(src[i]));
  s[threadIdx.x] = m; __syncthreads();
  for (int w = 128; w > 0; w >>= 1) {
    if (threadIdx.x < w) s[threadIdx.x] = fmaxf(s[threadIdx.x], s[threadIdx.x + w]);
    __syncthreads();
  }
  if (threadIdx.x == 0) atomicMax((int*)out, __float_as_int(s[0]));
}

__global__ void quant_w(const float* __restrict__ w, const float* __restrict__ scales,
                        signed char* __restrict__ wq, int n) {
  int i = blockIdx.x * 256 + threadIdx.x;
  if (i < n) {
    float inv = 127.0f / scales[0];
    int q = (int)rintf(w[i] * inv);
    q = max(-127, min(127, q));
    wq[i] = (signed char)q;
  }
}

__global__ void cast_f32_f16(const float* __restrict__ src, unsigned short* __restrict__ dst, int n) {
  int i = (blockIdx.x * 256 + threadIdx.x) * 4;
  if (i < n) {
    f32x4 v = *(const f32x4*)(src + i);
    ushort4 pk;
    pk.x = f2h(v[0]); pk.y = f2h(v[1]); pk.z = f2h(v[2]); pk.w = f2h(v[3]);
    *(ushort4*)(dst + i) = pk;
  }
}

__global__ void state_init(const float* __restrict__ h0, const float* __restrict__ c0,
                           const float* __restrict__ scales,
                           signed char* __restrict__ hst, float* __restrict__ cst) {
  int i = blockIdx.x * 256 + threadIdx.x;  // grid 512 -> 131072
  float inv = 127.0f / scales[1];
  int q = (int)rintf(h0[i] * inv);
  q = max(-127, min(127, q));
  hst[i] = (signed char)q;
  cst[i] = c0[i];
}

__global__ void finalize(const float* __restrict__ cst, float* __restrict__ out) {
  int i = blockIdx.x * 256 + threadIdx.x;
  out[i] = cst[i];
}

// ---------------------------------------------------------------- phase 1
__global__ __launch_bounds__(256) void xgemm(
    const float* __restrict__ x, const unsigned short* __restrict__ wih,
    const float* __restrict__ b_ih, const float* __restrict__ b_hh,
    unsigned short* __restrict__ xg, int t0, int tclog) {
  __shared__ unsigned short Ash[128 * 128];
  __shared__ unsigned short Bsh[128 * 128];

  const int tid  = threadIdx.x;
  const int lane = tid & 63;
  const int wv   = tid >> 6;
  const int c16  = lane & 15;
  const int gq   = lane >> 4;
  const long m0  = (long)blockIdx.x * 128;
  const int tcm  = (1 << tclog) - 1;

#pragma unroll
  for (int i = 0; i < 16; ++i) {
    int fidx = (i * 256 + tid) * 4;
    int row = fidx >> 7, k = fidx & 127;
    long cr = m0 + row;
    long b  = cr >> tclog;
    long tl = cr & tcm;
    f32x4 v = *(const f32x4*)(x + ((size_t)b * 512 + t0 + tl) * 128 + k);
    ushort4 pk;
    pk.x = f2h(v[0]); pk.y = f2h(v[1]); pk.z = f2h(v[2]); pk.w = f2h(v[3]);
    int byte = (row * 256 + k * 2) ^ ((row & 7) << 4);
    *(ushort4*)((char*)Ash + byte) = pk;
  }

  const int mh = (wv >> 1) * 64;
  const int nh = (wv & 1) * 64;

  for (int nc = 0; nc < 8; ++nc) {
    __syncthreads();
    {
      const char* wb = (const char*)(wih + nc * 128 * 128);
#pragma unroll
      for (int i = 0; i < 8; ++i) {
        int idx16 = i * 256 + tid;
        int row = idx16 >> 4, ch = idx16 & 15;
        int srcoff = row * 256 + ((ch * 16) ^ ((row & 7) << 4));
        u32x4 v = *(const u32x4*)(wb + srcoff);
        *(u32x4*)((char*)Bsh + idx16 * 16) = v;
      }
    }
    __syncthreads();

    float bias_v[4];
#pragma unroll
    for (int nt = 0; nt < 4; ++nt) {
      int gc = nc * 128 + nh + nt * 16 + c16;
      bias_v[nt] = b_ih[gc] + b_hh[gc];
    }

    f16x8 af[4][4], bfr[4][4];
#pragma unroll
    for (int sm = 0; sm < 4; ++sm)
#pragma unroll
      for (int kt = 0; kt < 4; ++kt) {
        int m = mh + sm * 16 + c16;
        int byte = (m * 256 + (kt * 32 + gq * 8) * 2) ^ ((m & 7) << 4);
        af[sm][kt] = __builtin_bit_cast(f16x8, *(const u32x4*)((const char*)Ash + byte));
      }
#pragma unroll
    for (int nt = 0; nt < 4; ++nt)
#pragma unroll
      for (int kt = 0; kt < 4; ++kt) {
        int n = nh + nt * 16 + c16;
        int byte = (n * 256 + (kt * 32 + gq * 8) * 2) ^ ((n & 7) << 4);
        bfr[nt][kt] = __builtin_bit_cast(f16x8, *(const u32x4*)((const char*)Bsh + byte));
      }

    f32x4 acc[4][4];
#pragma unroll
    for (int sm = 0; sm < 4; ++sm)
#pragma unroll
      for (int nt = 0; nt < 4; ++nt) { f32x4 z = {0.f, 0.f, 0.f, 0.f}; acc[sm][nt] = z; }
#pragma unroll
    for (int sm = 0; sm < 4; ++sm)
#pragma unroll
      for (int nt = 0; nt < 4; ++nt)
#pragma unroll
        for (int kt = 0; kt < 4; ++kt)
          acc[sm][nt] = __builtin_amdgcn_mfma_f32_16x16x32_f16(af[sm][kt], bfr[nt][kt], acc[sm][nt], 0, 0, 0);

#pragma unroll
    for (int sm = 0; sm < 4; ++sm)
#pragma unroll
      for (int nt = 0; nt < 4; ++nt) {
        long row = m0 + mh + sm * 16 + gq * 4;
        int gcol = nc * 128 + nh + nt * 16 + c16;
#pragma unroll
        for (int r = 0; r < 4; ++r)
          xg[(size_t)(row + r) * 1024 + gcol] = f2h(acc[sm][nt][r] + bias_v[nt]);
      }
  }
}

// ---------------------------------------------------------------- phase 2
// 256 blocks x 512 thr. Wave wv owns gate cols {g*256 + wv*32 + [0,32)}, g=0..3.
// Real batch rows at M-rows 0 and 8 -> D rows land in (gq=0,r=0) and (gq=2,r=0).
// w_hh i8 fully in regs: wf[nt][kt], nt = g*2+ntc (8), kt = K/64 (4) -> 128 VGPR.
__global__ __launch_bounds__(512, 2) void lstm_chunk(
    const unsigned short* __restrict__ xg, const signed char* __restrict__ wq,
    const float* __restrict__ scales,
    signed char* __restrict__ hst, float* __restrict__ cst, int Tc, int first) {
  __shared__ char hb[2][4096];  // [buf][16 rows x 256 cols] i8, XOR-swizzled

  const int tid  = threadIdx.x;
  const int lane = tid & 63;
  const int wv   = tid >> 6;      // 0..7
  const int c16  = lane & 15;
  const int gq   = lane >> 4;     // 0..3
  const int b0   = blockIdx.x * 2;

  // persistent weights: n = (nt>>1)*256 + wv*32 + (nt&1)*16 + c16 ; k = kt*64+gq*16
  i32x4 wf[8][4];
#pragma unroll
  for (int nt = 0; nt < 8; ++nt)
#pragma unroll
    for (int kt = 0; kt < 4; ++kt) {
      int n = (nt >> 1) * 256 + wv * 32 + (nt & 1) * 16 + c16;
      wf[nt][kt] = *(const i32x4*)(wq + n * 256 + kt * 64 + gq * 16);
    }

  // init both h buffers: rows 0/8 = batch b0/b0+1; rest zero
  for (int i = tid; i < 8192; i += 512) {
    int buf = i >> 12, idx = i & 4095;
    int row = idx >> 8, col = idx & 255;
    signed char v = 0;
    if (row == 0) v = hst[b0 * 256 + col];
    else if (row == 8) v = hst[(b0 + 1) * 256 + col];
    hb[buf][(row * 256 + col) ^ ((row & 7) << 4)] = v;
  }

  const int act  = ((gq & 1) == 0);   // gq 0 or 2
  const int arow = gq >> 1;           // batch row offset 0/1 (valid when act)
  const int col0 = wv * 32 + c16;     // ntc=0 col; +16 for ntc=1

  float cv0 = 0.f, cv1 = 0.f;
  if (act) {
    cv0 = cst[(b0 + arow) * 256 + col0];
    cv1 = cst[(b0 + arow) * 256 + col0 + 16];
  }

  const float sw   = scales[0] * (1.0f / 127.0f);
  const float facR = sw * (1.0f / 127.0f);
  const float fac0 = first ? sw * (scales[1] * (1.0f / 127.0f)) : facR;

  __syncthreads();

  for (int tt = 0; tt < Tc; ++tt) {
    const int cur = tt & 1;

    // issue xg loads early (consumed after MFMA phase)
    unsigned short xr0=0,xr1=0,xr2=0,xr3=0,xr4=0,xr5=0,xr6=0,xr7=0;
    if (act) {
      const unsigned short* xp = xg + ((size_t)(b0 + arow) * Tc + tt) * 1024 + wv * 32 + c16;
      xr0 = xp[0];   xr1 = xp[16];
      xr2 = xp[256]; xr3 = xp[272];
      xr4 = xp[512]; xr5 = xp[528];
      xr6 = xp[768]; xr7 = xp[784];
    }

    // A fragments: rows = c16 (M), k = kt*64 + gq*16, 16 bytes, swizzled
    i32x4 af[4];
#pragma unroll
    for (int kt = 0; kt < 4; ++kt)
      af[kt] = *(const i32x4*)(&hb[cur][(c16 * 256 + kt * 64 + gq * 16) ^ ((c16 & 7) << 4)]);

    i32x4 acc[8];
#pragma unroll
    for (int nt = 0; nt < 8; ++nt) { i32x4 z = {0, 0, 0, 0}; acc[nt] = z; }
#pragma unroll
    for (int kt = 0; kt < 4; ++kt)
#pragma unroll
      for (int nt = 0; nt < 8; ++nt)
        acc[nt] = __builtin_amdgcn_mfma_i32_16x16x64_i8(af[kt], wf[nt][kt], acc[nt], 0, 0, 0);

    const float fac = (tt == 0) ? fac0 : facR;

    if (act) {
      // ntc = 0
      {
        float gi = (float)acc[0][0] * fac + h2f(xr0);
        float gf = (float)acc[2][0] * fac + h2f(xr2);
        float gg = (float)acc[4][0] * fac + h2f(xr4);
        float go = (float)acc[6][0] * fac + h2f(xr6);
        cv0 = fast_sigmoid(gf) * cv0 + fast_sigmoid(gi) * fast_tanh(gg);
        float hn = fast_sigmoid(go) * fast_tanh(cv0);
        int q = (int)rintf(hn * 127.0f);
        q = max(-127, min(127, q));
        hb[cur ^ 1][arow * 2048 + col0] = (signed char)q;  // rows 0/8: swizzle = 0
      }
      // ntc = 1
      {
        float gi = (float)acc[1][0] * fac + h2f(xr1);
        float gf = (float)acc[3][0] * fac + h2f(xr3);
        float gg = (float)acc[5][0] * fac + h2f(xr5);
        float go = (float)acc[7][0] * fac + h2f(xr7);
        cv1 = fast_sigmoid(gf) * cv1 + fast_sigmoid(gi) * fast_tanh(gg);
        float hn = fast_sigmoid(go) * fast_tanh(cv1);
        int q = (int)rintf(hn * 127.0f);
        q = max(-127, min(127, q));
        hb[cur ^ 1][arow * 2048 + col0 + 16] = (signed char)q;
      }
    }
    __syncthreads();
  }

  if (act) {
    cst[(b0 + arow) * 256 + col0]      = cv0;
    cst[(b0 + arow) * 256 + col0 + 16] = cv1;
    hst[(b0 + arow) * 256 + col0]      = hb[Tc & 1][arow * 2048 + col0];
    hst[(b0 + arow) * 256 + col0 + 16] = hb[Tc & 1][arow * 2048 + col0 + 16];
  }
}

// ---------------------------------------------------------------- launch
extern "C" void kernel_launch(void* const* d_in, const int* in_sizes, int n_in,
                              void* d_out, int out_size, void* d_ws, size_t ws_size,
                              hipStream_t stream) {
  const float* x   = (const float*)d_in[0];
  const float* h0  = (const float*)d_in[1];
  const float* c0  = (const float*)d_in[2];
  const float* wih = (const float*)d_in[3];
  const float* whh = (const float*)d_in[4];
  const float* bih = (const float*)d_in[5];
  const float* bhh = (const float*)d_in[6];
  float* out = (float*)d_out;

  const size_t fixed = 262144u /*wih f16*/ + 262144u /*wq*/ + 131072u /*hst*/
                     + 524288u /*cst*/ + 256u /*scales*/;
  int tc = 512;
  while (tc > 4 && (size_t)512 * tc * 2048 + fixed > ws_size) tc >>= 1;
  int tclog = 31 - __builtin_clz((unsigned)tc);

  char* ws = (char*)d_ws;
  unsigned short* xgb   = (unsigned short*)ws;
  size_t off = (size_t)512 * tc * 2048;
  unsigned short* wih_h = (unsigned short*)(ws + off);  off += 262144u;
  signed char*    wqb   = (signed char*)(ws + off);     off += 262144u;
  signed char*    hst   = (signed char*)(ws + off);     off += 131072u;
  float*          cst   = (float*)(ws + off);           off += 524288u;
  float*          scl   = (float*)(ws + off);

  zero2<<<1, 64, 0, stream>>>(scl);
  absmax_red<<<128, 256, 0, stream>>>(whh, 262144, scl + 0);
  absmax_red<<<64, 256, 0, stream>>>(h0, 131072, scl + 1);
  cast_f32_f16<<<128, 256, 0, stream>>>(wih, wih_h, 131072);
  quant_w<<<1024, 256, 0, stream>>>(whh, scl, wqb, 262144);
  state_init<<<512, 256, 0, stream>>>(h0, c0, scl, hst, cst);

  int nchunks = 512 / tc;
  for (int c = 0; c < nchunks; ++c) {
    xgemm<<<4 * tc, 256, 0, stream>>>(x, wih_h, bih, bhh, xgb, c * tc, tclog);
    lstm_chunk<<<256, 512, 0, stream>>>(xgb, wqb, scl, hst, cst, tc, c == 0 ? 1 : 0);
  }
  finalize<<<512, 256, 0, stream>>>(cst, out);
}

// Round 4
// 638.813 us; speedup vs baseline: 2.7323x; 1.3895x over previous
//
#include <hip/hip_runtime.h>
#include <hip/hip_bf16.h>
#include <hip/hip_fp16.h>

// LSTM: B=512, T=512, I=128, H=256, gates G=4H=1024 (PyTorch i,f,g,o order).
// Phase 1 (per chunk): xgemm -> xg[B][Tc][col*4+gate] f16 (gate-interleaved via
//   row-permuted w_ih; biases folded in). Phase 2: lstm_chunk, 256 blocks x 8
//   waves; full w_hh i8 in 128 regs/thread; post-MFMA ds_bpermute spreads the
//   gates to all 64 lanes (1 output/lane); 1 barrier/step.

typedef __attribute__((ext_vector_type(4))) float f32x4;
typedef __attribute__((ext_vector_type(8))) _Float16 f16x8;
typedef __attribute__((ext_vector_type(4))) unsigned int u32x4;
typedef __attribute__((ext_vector_type(4))) int i32x4;

static __device__ __forceinline__ float h2f(unsigned short u) {
  return (float)__builtin_bit_cast(_Float16, u);
}
static __device__ __forceinline__ unsigned short f2h(float f) {
  return __builtin_bit_cast(unsigned short, (_Float16)f);
}
static __device__ __forceinline__ float fast_sigmoid(float x) {
  return __builtin_amdgcn_rcpf(1.0f + __builtin_amdgcn_exp2f(-1.44269504f * x));
}
static __device__ __forceinline__ float fast_tanh(float x) {
  return 1.0f - 2.0f * __builtin_amdgcn_rcpf(1.0f + __builtin_amdgcn_exp2f(2.88539008f * x));
}

// ---------------------------------------------------------------- small utils
__global__ void zero2(float* p) { if (threadIdx.x < 2) p[threadIdx.x] = 0.f; }

__global__ void absmax_red(const float* __restrict__ src, int n, float* __restrict__ out) {
  __shared__ float s[256];
  float m = 0.f;
  for (int i = blockIdx.x * 256 + threadIdx.x; i < n; i += gridDim.x * 256)
    m = fmaxf(m, fabsf(src[i]));
  s[threadIdx.x] = m; __syncthreads();
  for (int w = 128; w > 0; w >>= 1) {
    if (threadIdx.x < w) s[threadIdx.x] = fmaxf(s[threadIdx.x], s[threadIdx.x + w]);
    __syncthreads();
  }
  if (threadIdx.x == 0) atomicMax((int*)out, __float_as_int(s[0]));
}

__global__ void quant_w(const float* __restrict__ w, const float* __restrict__ scales,
                        signed char* __restrict__ wq, int n) {
  int i = blockIdx.x * 256 + threadIdx.x;
  if (i < n) {
    float inv = 127.0f / scales[0];
    int q = (int)rintf(w[i] * inv);
    q = max(-127, min(127, q));
    wq[i] = (signed char)q;
  }
}

// w_ih cast with gate-row interleave: dst row q <- src row (q&3)*256 + (q>>2)
__global__ void wperm_cast(const float* __restrict__ w, unsigned short* __restrict__ dst) {
  int i = (blockIdx.x * 256 + threadIdx.x) * 4;  // over 131072
  if (i < 131072) {
    int q = i >> 7, k = i & 127;
    int p = (q & 3) * 256 + (q >> 2);
    f32x4 v = *(const f32x4*)(w + p * 128 + k);
    ushort4 pk;
    pk.x = f2h(v[0]); pk.y = f2h(v[1]); pk.z = f2h(v[2]); pk.w = f2h(v[3]);
    *(ushort4*)(dst + i) = pk;
  }
}

__global__ void bias_perm(const float* __restrict__ bi, const float* __restrict__ bh,
                          float* __restrict__ bc) {
  int q = blockIdx.x * 256 + threadIdx.x;  // 1024
  int p = (q & 3) * 256 + (q >> 2);
  bc[q] = bi[p] + bh[p];
}

__global__ void state_init(const float* __restrict__ h0, const float* __restrict__ c0,
                           const float* __restrict__ scales,
                           signed char* __restrict__ hst, float* __restrict__ cst) {
  int i = blockIdx.x * 256 + threadIdx.x;  // grid 512 -> 131072
  float inv = 127.0f / scales[1];
  int q = (int)rintf(h0[i] * inv);
  q = max(-127, min(127, q));
  hst[i] = (signed char)q;
  cst[i] = c0[i];
}

__global__ void finalize(const float* __restrict__ cst, float* __restrict__ out) {
  int i = blockIdx.x * 256 + threadIdx.x;
  out[i] = cst[i];
}

// ---------------------------------------------------------------- phase 1
// Unchanged GEMM; wih is the row-permuted f16 copy, bias from bconv, so output
// col n IS the interleaved index q = col*4+gate. Writes stay fully coalesced.
__global__ __launch_bounds__(256) void xgemm(
    const float* __restrict__ x, const unsigned short* __restrict__ wih,
    const float* __restrict__ bconv,
    unsigned short* __restrict__ xg, int t0, int tclog) {
  __shared__ unsigned short Ash[128 * 128];
  __shared__ unsigned short Bsh[128 * 128];

  const int tid  = threadIdx.x;
  const int lane = tid & 63;
  const int wv   = tid >> 6;
  const int c16  = lane & 15;
  const int gq   = lane >> 4;
  const long m0  = (long)blockIdx.x * 128;
  const int tcm  = (1 << tclog) - 1;

#pragma unroll
  for (int i = 0; i < 16; ++i) {
    int fidx = (i * 256 + tid) * 4;
    int row = fidx >> 7, k = fidx & 127;
    long cr = m0 + row;
    long b  = cr >> tclog;
    long tl = cr & tcm;
    f32x4 v = *(const f32x4*)(x + ((size_t)b * 512 + t0 + tl) * 128 + k);
    ushort4 pk;
    pk.x = f2h(v[0]); pk.y = f2h(v[1]); pk.z = f2h(v[2]); pk.w = f2h(v[3]);
    int byte = (row * 256 + k * 2) ^ ((row & 7) << 4);
    *(ushort4*)((char*)Ash + byte) = pk;
  }

  const int mh = (wv >> 1) * 64;
  const int nh = (wv & 1) * 64;

  for (int nc = 0; nc < 8; ++nc) {
    __syncthreads();
    {
      const char* wb = (const char*)(wih + nc * 128 * 128);
#pragma unroll
      for (int i = 0; i < 8; ++i) {
        int idx16 = i * 256 + tid;
        int row = idx16 >> 4, ch = idx16 & 15;
        int srcoff = row * 256 + ((ch * 16) ^ ((row & 7) << 4));
        u32x4 v = *(const u32x4*)(wb + srcoff);
        *(u32x4*)((char*)Bsh + idx16 * 16) = v;
      }
    }
    __syncthreads();

    float bias_v[4];
#pragma unroll
    for (int nt = 0; nt < 4; ++nt)
      bias_v[nt] = bconv[nc * 128 + nh + nt * 16 + c16];

    f16x8 af[4][4], bfr[4][4];
#pragma unroll
    for (int sm = 0; sm < 4; ++sm)
#pragma unroll
      for (int kt = 0; kt < 4; ++kt) {
        int m = mh + sm * 16 + c16;
        int byte = (m * 256 + (kt * 32 + gq * 8) * 2) ^ ((m & 7) << 4);
        af[sm][kt] = __builtin_bit_cast(f16x8, *(const u32x4*)((const char*)Ash + byte));
      }
#pragma unroll
    for (int nt = 0; nt < 4; ++nt)
#pragma unroll
      for (int kt = 0; kt < 4; ++kt) {
        int n = nh + nt * 16 + c16;
        int byte = (n * 256 + (kt * 32 + gq * 8) * 2) ^ ((n & 7) << 4);
        bfr[nt][kt] = __builtin_bit_cast(f16x8, *(const u32x4*)((const char*)Bsh + byte));
      }

    f32x4 acc[4][4];
#pragma unroll
    for (int sm = 0; sm < 4; ++sm)
#pragma unroll
      for (int nt = 0; nt < 4; ++nt) { f32x4 z = {0.f, 0.f, 0.f, 0.f}; acc[sm][nt] = z; }
#pragma unroll
    for (int sm = 0; sm < 4; ++sm)
#pragma unroll
      for (int nt = 0; nt < 4; ++nt)
#pragma unroll
        for (int kt = 0; kt < 4; ++kt)
          acc[sm][nt] = __builtin_amdgcn_mfma_f32_16x16x32_f16(af[sm][kt], bfr[nt][kt], acc[sm][nt], 0, 0, 0);

#pragma unroll
    for (int sm = 0; sm < 4; ++sm)
#pragma unroll
      for (int nt = 0; nt < 4; ++nt) {
        long row = m0 + mh + sm * 16 + gq * 4;
        int gcol = nc * 128 + nh + nt * 16 + c16;
#pragma unroll
        for (int r = 0; r < 4; ++r)
          xg[(size_t)(row + r) * 1024 + gcol] = f2h(acc[sm][nt][r] + bias_v[nt]);
      }
  }
}

// ---------------------------------------------------------------- phase 2
// 256 blocks x 512 thr. Wave wv owns gate cols {g*256 + wv*32 + [0,32)}.
// Real batch rows at M-rows 0 (b0) and 8 (b0+1). After MFMA, ds_bpermute
// spreads gates so lane L handles output (arow=L>>5, col=wv*32+(L&31)).
__global__ __launch_bounds__(512, 2) void lstm_chunk(
    const unsigned short* __restrict__ xg, const signed char* __restrict__ wq,
    const float* __restrict__ scales,
    signed char* __restrict__ hst, float* __restrict__ cst, int Tc, int first) {
  __shared__ char hb[2][4096];  // [buf][16 rows x 256 cols] i8, XOR-swizzled

  const int tid  = threadIdx.x;
  const int lane = tid & 63;
  const int wv   = tid >> 6;      // 0..7
  const int c16  = lane & 15;
  const int gq   = lane >> 4;     // 0..3
  const int b0   = blockIdx.x * 2;

  // persistent weights: n = (nt>>1)*256 + wv*32 + (nt&1)*16 + c16 ; k = kt*64+gq*16
  i32x4 wf[8][4];
#pragma unroll
  for (int nt = 0; nt < 8; ++nt)
#pragma unroll
    for (int kt = 0; kt < 4; ++kt) {
      int n = (nt >> 1) * 256 + wv * 32 + (nt & 1) * 16 + c16;
      wf[nt][kt] = *(const i32x4*)(wq + n * 256 + kt * 64 + gq * 16);
    }

  // init both h buffers: rows 0/8 = batch b0/b0+1; rest zero
  for (int i = tid; i < 8192; i += 512) {
    int buf = i >> 12, idx = i & 4095;
    int row = idx >> 8, col = idx & 255;
    signed char v = 0;
    if (row == 0) v = hst[b0 * 256 + col];
    else if (row == 8) v = hst[(b0 + 1) * 256 + col];
    hb[buf][(row * 256 + col) ^ ((row & 7) << 4)] = v;
  }

  const int arow = lane >> 5;            // 0/1 -> batch row
  const int colw = lane & 31;            // col within wave
  const int col  = wv * 32 + colw;
  const int bsel = (lane & 16) != 0;     // ntc: pick odd acc
  const int bpidx = (arow * 32 + c16) * 4;  // bpermute byte index (src lane*4)

  float cv = cst[(b0 + arow) * 256 + col];

  const float sw   = scales[0] * (1.0f / 127.0f);
  const float facR = sw * (1.0f / 127.0f);
  const float fac0 = first ? sw * (scales[1] * (1.0f / 127.0f)) : facR;

  // per-lane xg pointer: [row][tt][col*4 + g], ushort4 per lane per step
  const ushort4* xp = (const ushort4*)(xg + ((size_t)(b0 + arow) * Tc) * 1024 + col * 4);

  __syncthreads();

  ushort4 px = xp[0];   // t = 0
  const i32x4 zacc = {0, 0, 0, 0};

  for (int tt = 0; tt < Tc; ++tt) {
    const int cur = tt & 1;

    // prefetch next step's xg (full MFMA phase of latency cover)
    int tn = (tt + 1 < Tc) ? tt + 1 : Tc - 1;
    ushort4 pn = xp[(size_t)tn * 256];

    // A fragments: M-row = c16, k = kt*64 + gq*16 (swizzled b128 reads)
    i32x4 af[4];
#pragma unroll
    for (int kt = 0; kt < 4; ++kt)
      af[kt] = *(const i32x4*)(&hb[cur][(c16 * 256 + kt * 64 + gq * 16) ^ ((c16 & 7) << 4)]);

    i32x4 acc[8];
#pragma unroll
    for (int nt = 0; nt < 8; ++nt)
      acc[nt] = __builtin_amdgcn_mfma_i32_16x16x64_i8(af[0], wf[nt][0], zacc, 0, 0, 0);
#pragma unroll
    for (int kt = 1; kt < 4; ++kt)
#pragma unroll
      for (int nt = 0; nt < 8; ++nt)
        acc[nt] = __builtin_amdgcn_mfma_i32_16x16x64_i8(af[kt], wf[nt][kt], acc[nt], 0, 0, 0);

    // redistribute: all 64 lanes get their output's 4 gate sums
    float ga[4];
#pragma unroll
    for (int g = 0; g < 4; ++g) {
      int e = __builtin_amdgcn_ds_bpermute(bpidx, acc[2 * g][0]);
      int o = __builtin_amdgcn_ds_bpermute(bpidx, acc[2 * g + 1][0]);
      ga[g] = (float)(bsel ? o : e);
    }

    const float fac = (tt == 0) ? fac0 : facR;

    float gi = __builtin_fmaf(ga[0], fac, h2f(px.x));
    float gf = __builtin_fmaf(ga[1], fac, h2f(px.y));
    float gg = __builtin_fmaf(ga[2], fac, h2f(px.z));
    float go = __builtin_fmaf(ga[3], fac, h2f(px.w));

    float ig = fast_sigmoid(gi);
    float fg = fast_sigmoid(gf);
    float gt = fast_tanh(gg);
    float og = fast_sigmoid(go);
    cv = fg * cv + ig * gt;
    float hn = og * fast_tanh(cv);
    int q = (int)rintf(hn * 127.0f);        // |hn| < 1 -> no clamp needed
    hb[cur ^ 1][arow * 2048 + col] = (signed char)q;  // rows 0/8: swizzle = 0

    px = pn;
    __syncthreads();
  }

  cst[(b0 + arow) * 256 + col] = cv;
  hst[(b0 + arow) * 256 + col] = hb[Tc & 1][arow * 2048 + col];
}

// ---------------------------------------------------------------- launch
extern "C" void kernel_launch(void* const* d_in, const int* in_sizes, int n_in,
                              void* d_out, int out_size, void* d_ws, size_t ws_size,
                              hipStream_t stream) {
  const float* x   = (const float*)d_in[0];
  const float* h0  = (const float*)d_in[1];
  const float* c0  = (const float*)d_in[2];
  const float* wih = (const float*)d_in[3];
  const float* whh = (const float*)d_in[4];
  const float* bih = (const float*)d_in[5];
  const float* bhh = (const float*)d_in[6];
  float* out = (float*)d_out;

  const size_t fixed = 262144u /*wih f16*/ + 262144u /*wq*/ + 131072u /*hst*/
                     + 524288u /*cst*/ + 4096u /*bconv*/ + 256u /*scales*/;
  int tc = 512;
  while (tc > 4 && (size_t)512 * tc * 2048 + fixed > ws_size) tc >>= 1;
  int tclog = 31 - __builtin_clz((unsigned)tc);

  char* ws = (char*)d_ws;
  unsigned short* xgb   = (unsigned short*)ws;
  size_t off = (size_t)512 * tc * 2048;
  unsigned short* wih_h = (unsigned short*)(ws + off);  off += 262144u;
  signed char*    wqb   = (signed char*)(ws + off);     off += 262144u;
  signed char*    hst   = (signed char*)(ws + off);     off += 131072u;
  float*          cst   = (float*)(ws + off);           off += 524288u;
  float*          bcv   = (float*)(ws + off);           off += 4096u;
  float*          scl   = (float*)(ws + off);

  zero2<<<1, 64, 0, stream>>>(scl);
  absmax_red<<<128, 256, 0, stream>>>(whh, 262144, scl + 0);
  absmax_red<<<64, 256, 0, stream>>>(h0, 131072, scl + 1);
  wperm_cast<<<128, 256, 0, stream>>>(wih, wih_h);
  bias_perm<<<4, 256, 0, stream>>>(bih, bhh, bcv);
  quant_w<<<1024, 256, 0, stream>>>(whh, scl, wqb, 262144);
  state_init<<<512, 256, 0, stream>>>(h0, c0, scl, hst, cst);

  int nchunks = 512 / tc;
  for (int c = 0; c < nchunks; ++c) {
    xgemm<<<4 * tc, 256, 0, stream>>>(x, wih_h, bcv, xgb, c * tc, tclog);
    lstm_chunk<<<256, 512, 0, stream>>>(xgb, wqb, scl, hst, cst, tc, c == 0 ? 1 : 0);
  }
  finalize<<<512, 256, 0, stream>>>(cst, out);
}

// Round 5
// 587.884 us; speedup vs baseline: 2.9690x; 1.0866x over previous
//
#include <hip/hip_runtime.h>
#include <hip/hip_bf16.h>
#include <hip/hip_fp16.h>

// LSTM: B=512, T=512, I=128, H=256, gates G=4H=1024 (PyTorch i,f,g,o order).
// Phase 1 (per chunk): xgemm -> xg[B][Tc][col*4+gate] f16 (gate-interleaved via
//   row-permuted w_ih; biases folded in). Phase 2: lstm_chunk, 256 blocks x 8
//   waves; full w_hh i8 in 128 regs/thread; A-frags exec-masked (only M-rows
//   0/8 are real); post-MFMA ds_swizzle xor-16 spreads gates to all 64 lanes;
//   1 barrier/step.

typedef __attribute__((ext_vector_type(4))) float f32x4;
typedef __attribute__((ext_vector_type(8))) _Float16 f16x8;
typedef __attribute__((ext_vector_type(4))) unsigned int u32x4;
typedef __attribute__((ext_vector_type(4))) int i32x4;

static __device__ __forceinline__ float h2f(unsigned short u) {
  return (float)__builtin_bit_cast(_Float16, u);
}
static __device__ __forceinline__ unsigned short f2h(float f) {
  return __builtin_bit_cast(unsigned short, (_Float16)f);
}
static __device__ __forceinline__ float fast_sigmoid(float x) {
  return __builtin_amdgcn_rcpf(1.0f + __builtin_amdgcn_exp2f(-1.44269504f * x));
}
static __device__ __forceinline__ float fast_tanh(float x) {
  return 1.0f - 2.0f * __builtin_amdgcn_rcpf(1.0f + __builtin_amdgcn_exp2f(2.88539008f * x));
}

// ---------------------------------------------------------------- small utils
__global__ void zero2(float* p) { if (threadIdx.x < 2) p[threadIdx.x] = 0.f; }

__global__ void absmax_red(const float* __restrict__ src, int n, float* __restrict__ out) {
  __shared__ float s[256];
  float m = 0.f;
  for (int i = blockIdx.x * 256 + threadIdx.x; i < n; i += gridDim.x * 256)
    m = fmaxf(m, fabsf(src[i]));
  s[threadIdx.x] = m; __syncthreads();
  for (int w = 128; w > 0; w >>= 1) {
    if (threadIdx.x < w) s[threadIdx.x] = fmaxf(s[threadIdx.x], s[threadIdx.x + w]);
    __syncthreads();
  }
  if (threadIdx.x == 0) atomicMax((int*)out, __float_as_int(s[0]));
}

__global__ void quant_w(const float* __restrict__ w, const float* __restrict__ scales,
                        signed char* __restrict__ wq, int n) {
  int i = blockIdx.x * 256 + threadIdx.x;
  if (i < n) {
    float inv = 127.0f / scales[0];
    int q = (int)rintf(w[i] * inv);
    q = max(-127, min(127, q));
    wq[i] = (signed char)q;
  }
}

// w_ih cast with gate-row interleave: dst row q <- src row (q&3)*256 + (q>>2)
__global__ void wperm_cast(const float* __restrict__ w, unsigned short* __restrict__ dst) {
  int i = (blockIdx.x * 256 + threadIdx.x) * 4;  // over 131072
  if (i < 131072) {
    int q = i >> 7, k = i & 127;
    int p = (q & 3) * 256 + (q >> 2);
    f32x4 v = *(const f32x4*)(w + p * 128 + k);
    ushort4 pk;
    pk.x = f2h(v[0]); pk.y = f2h(v[1]); pk.z = f2h(v[2]); pk.w = f2h(v[3]);
    *(ushort4*)(dst + i) = pk;
  }
}

__global__ void bias_perm(const float* __restrict__ bi, const float* __restrict__ bh,
                          float* __restrict__ bc) {
  int q = blockIdx.x * 256 + threadIdx.x;  // 1024
  int p = (q & 3) * 256 + (q >> 2);
  bc[q] = bi[p] + bh[p];
}

__global__ void state_init(const float* __restrict__ h0, const float* __restrict__ c0,
                           const float* __restrict__ scales,
                           signed char* __restrict__ hst, float* __restrict__ cst) {
  int i = blockIdx.x * 256 + threadIdx.x;  // grid 512 -> 131072
  float inv = 127.0f / scales[1];
  int q = (int)rintf(h0[i] * inv);
  q = max(-127, min(127, q));
  hst[i] = (signed char)q;
  cst[i] = c0[i];
}

__global__ void finalize(const float* __restrict__ cst, float* __restrict__ out) {
  int i = blockIdx.x * 256 + threadIdx.x;
  out[i] = cst[i];
}

// ---------------------------------------------------------------- phase 1
__global__ __launch_bounds__(256) void xgemm(
    const float* __restrict__ x, const unsigned short* __restrict__ wih,
    const float* __restrict__ bconv,
    unsigned short* __restrict__ xg, int t0, int tclog) {
  __shared__ unsigned short Ash[128 * 128];
  __shared__ unsigned short Bsh[128 * 128];

  const int tid  = threadIdx.x;
  const int lane = tid & 63;
  const int wv   = tid >> 6;
  const int c16  = lane & 15;
  const int gq   = lane >> 4;
  const long m0  = (long)blockIdx.x * 128;
  const int tcm  = (1 << tclog) - 1;

#pragma unroll
  for (int i = 0; i < 16; ++i) {
    int fidx = (i * 256 + tid) * 4;
    int row = fidx >> 7, k = fidx & 127;
    long cr = m0 + row;
    long b  = cr >> tclog;
    long tl = cr & tcm;
    f32x4 v = *(const f32x4*)(x + ((size_t)b * 512 + t0 + tl) * 128 + k);
    ushort4 pk;
    pk.x = f2h(v[0]); pk.y = f2h(v[1]); pk.z = f2h(v[2]); pk.w = f2h(v[3]);
    int byte = (row * 256 + k * 2) ^ ((row & 7) << 4);
    *(ushort4*)((char*)Ash + byte) = pk;
  }

  const int mh = (wv >> 1) * 64;
  const int nh = (wv & 1) * 64;

  for (int nc = 0; nc < 8; ++nc) {
    __syncthreads();
    {
      const char* wb = (const char*)(wih + nc * 128 * 128);
#pragma unroll
      for (int i = 0; i < 8; ++i) {
        int idx16 = i * 256 + tid;
        int row = idx16 >> 4, ch = idx16 & 15;
        int srcoff = row * 256 + ((ch * 16) ^ ((row & 7) << 4));
        u32x4 v = *(const u32x4*)(wb + srcoff);
        *(u32x4*)((char*)Bsh + idx16 * 16) = v;
      }
    }
    __syncthreads();

    float bias_v[4];
#pragma unroll
    for (int nt = 0; nt < 4; ++nt)
      bias_v[nt] = bconv[nc * 128 + nh + nt * 16 + c16];

    f16x8 af[4][4], bfr[4][4];
#pragma unroll
    for (int sm = 0; sm < 4; ++sm)
#pragma unroll
      for (int kt = 0; kt < 4; ++kt) {
        int m = mh + sm * 16 + c16;
        int byte = (m * 256 + (kt * 32 + gq * 8) * 2) ^ ((m & 7) << 4);
        af[sm][kt] = __builtin_bit_cast(f16x8, *(const u32x4*)((const char*)Ash + byte));
      }
#pragma unroll
    for (int nt = 0; nt < 4; ++nt)
#pragma unroll
      for (int kt = 0; kt < 4; ++kt) {
        int n = nh + nt * 16 + c16;
        int byte = (n * 256 + (kt * 32 + gq * 8) * 2) ^ ((n & 7) << 4);
        bfr[nt][kt] = __builtin_bit_cast(f16x8, *(const u32x4*)((const char*)Bsh + byte));
      }

    f32x4 acc[4][4];
#pragma unroll
    for (int sm = 0; sm < 4; ++sm)
#pragma unroll
      for (int nt = 0; nt < 4; ++nt) { f32x4 z = {0.f, 0.f, 0.f, 0.f}; acc[sm][nt] = z; }
#pragma unroll
    for (int sm = 0; sm < 4; ++sm)
#pragma unroll
      for (int nt = 0; nt < 4; ++nt)
#pragma unroll
        for (int kt = 0; kt < 4; ++kt)
          acc[sm][nt] = __builtin_amdgcn_mfma_f32_16x16x32_f16(af[sm][kt], bfr[nt][kt], acc[sm][nt], 0, 0, 0);

#pragma unroll
    for (int sm = 0; sm < 4; ++sm)
#pragma unroll
      for (int nt = 0; nt < 4; ++nt) {
        long row = m0 + mh + sm * 16 + gq * 4;
        int gcol = nc * 128 + nh + nt * 16 + c16;
#pragma unroll
        for (int r = 0; r < 4; ++r)
          xg[(size_t)(row + r) * 1024 + gcol] = f2h(acc[sm][nt][r] + bias_v[nt]);
      }
  }
}

// ---------------------------------------------------------------- phase 2
// 256 blocks x 512 thr. Wave wv owns gate cols {g*256 + wv*32 + [0,32)}.
// Real batch rows at M-rows 0 (b0) and 8 (b0+1); A-loads exec-masked to
// lanes c16 in {0,8}; other lanes' af stay 0 (hoisted). Gate spread:
// lane L colw>=16 pulls acc_odd from L^16 via ds_swizzle.
__global__ __launch_bounds__(512, 2) void lstm_chunk(
    const unsigned short* __restrict__ xg, const signed char* __restrict__ wq,
    const float* __restrict__ scales,
    signed char* __restrict__ hst, float* __restrict__ cst, int Tc, int first) {
  __shared__ signed char hb[2][512];  // [buf][2 rows x 256 cols] i8

  const int tid  = threadIdx.x;
  const int lane = tid & 63;
  const int wv   = tid >> 6;      // 0..7
  const int c16  = lane & 15;
  const int gq   = lane >> 4;     // 0..3
  const int b0   = blockIdx.x * 2;

  // persistent weights: n = (nt>>1)*256 + wv*32 + (nt&1)*16 + c16 ; k = kt*64+gq*16
  i32x4 wf[8][4];
#pragma unroll
  for (int nt = 0; nt < 8; ++nt)
#pragma unroll
    for (int kt = 0; kt < 4; ++kt) {
      int n = (nt >> 1) * 256 + wv * 32 + (nt & 1) * 16 + c16;
      wf[nt][kt] = *(const i32x4*)(wq + n * 256 + kt * 64 + gq * 16);
    }

  // init hb[0]: [row(2)][col(256)] = hst slice (flat: hb[0][t] = hst[b0*256+t])
  hb[0][tid] = hst[b0 * 256 + tid];

  const int arow = lane >> 5;            // 0/1 -> batch row (elementwise role)
  const int colw = lane & 31;
  const int col  = wv * 32 + colw;
  const bool mrow = (c16 == 0) | (c16 == 8);  // A-load lanes
  const signed char* hp0 = &hb[0][(c16 >> 3) * 256 + gq * 16];

  float cv = cst[(b0 + arow) * 256 + col];
  int qlast = 0;

  const float sw   = scales[0] * (1.0f / 127.0f);
  const float facR = sw * (1.0f / 127.0f);
  const float fac0 = first ? sw * (scales[1] * (1.0f / 127.0f)) : facR;

  // per-lane xg pointer: [row][tt][col*4 + g], ushort4 per lane per step
  const char* pxp = (const char*)(xg + ((size_t)(b0 + arow) * Tc) * 1024 + col * 4);

  ushort4 px = *(const ushort4*)pxp;
  pxp += 2048;

  i32x4 af[4];
#pragma unroll
  for (int kt = 0; kt < 4; ++kt) { i32x4 z = {0, 0, 0, 0}; af[kt] = z; }
  const i32x4 zacc = {0, 0, 0, 0};

  __syncthreads();

  for (int tt = 0; tt < Tc; ++tt) {
    const int cur = tt & 1;

    // prefetch next step's xg (last iter reads into adjacent ws buffer; unused)
    ushort4 pn = *(const ushort4*)pxp;
    pxp += 2048;

    // A fragments: only lanes with real M-rows load; rest keep af = 0
    if (mrow) {
      const signed char* hp = hp0 + cur * 512;
      af[0] = *(const i32x4*)(hp);
      af[1] = *(const i32x4*)(hp + 64);
      af[2] = *(const i32x4*)(hp + 128);
      af[3] = *(const i32x4*)(hp + 192);
    }

    i32x4 acc[8];
#pragma unroll
    for (int nt = 0; nt < 8; ++nt)
      acc[nt] = __builtin_amdgcn_mfma_i32_16x16x64_i8(af[0], wf[nt][0], zacc, 0, 0, 0);
#pragma unroll
    for (int kt = 1; kt < 4; ++kt)
#pragma unroll
      for (int nt = 0; nt < 8; ++nt)
        acc[nt] = __builtin_amdgcn_mfma_i32_16x16x64_i8(af[kt], wf[nt][kt], acc[nt], 0, 0, 0);

    // spread: lane with colw>=16 takes acc_odd from lane L^16 (xor-16 swizzle)
    float ga[4];
#pragma unroll
    for (int g = 0; g < 4; ++g) {
      int o = __builtin_amdgcn_ds_swizzle(acc[2 * g + 1][0], 0x401F);
      int v = (colw < 16) ? acc[2 * g][0] : o;
      ga[g] = (float)v;
    }

    const float fac = (tt == 0) ? fac0 : facR;

    float gi = __builtin_fmaf(ga[0], fac, h2f(px.x));
    float gf = __builtin_fmaf(ga[1], fac, h2f(px.y));
    float gg = __builtin_fmaf(ga[2], fac, h2f(px.z));
    float go = __builtin_fmaf(ga[3], fac, h2f(px.w));

    float ig = fast_sigmoid(gi);
    float fg = fast_sigmoid(gf);
    float gt = fast_tanh(gg);
    float og = fast_sigmoid(go);
    cv = fg * cv + ig * gt;
    float hn = og * fast_tanh(cv);
    qlast = (int)rintf(hn * 127.0f);          // |hn| < 1 -> no clamp needed
    hb[cur ^ 1][arow * 256 + col] = (signed char)qlast;

    px = pn;
    __syncthreads();
  }

  cst[(b0 + arow) * 256 + col] = cv;
  hst[(b0 + arow) * 256 + col] = (signed char)qlast;
}

// ---------------------------------------------------------------- launch
extern "C" void kernel_launch(void* const* d_in, const int* in_sizes, int n_in,
                              void* d_out, int out_size, void* d_ws, size_t ws_size,
                              hipStream_t stream) {
  const float* x   = (const float*)d_in[0];
  const float* h0  = (const float*)d_in[1];
  const float* c0  = (const float*)d_in[2];
  const float* wih = (const float*)d_in[3];
  const float* whh = (const float*)d_in[4];
  const float* bih = (const float*)d_in[5];
  const float* bhh = (const float*)d_in[6];
  float* out = (float*)d_out;

  const size_t fixed = 262144u /*wih f16*/ + 262144u /*wq*/ + 131072u /*hst*/
                     + 524288u /*cst*/ + 4096u /*bconv*/ + 256u /*scales*/;
  int tc = 512;
  while (tc > 4 && (size_t)512 * tc * 2048 + fixed > ws_size) tc >>= 1;
  int tclog = 31 - __builtin_clz((unsigned)tc);

  char* ws = (char*)d_ws;
  unsigned short* xgb   = (unsigned short*)ws;
  size_t off = (size_t)512 * tc * 2048;
  unsigned short* wih_h = (unsigned short*)(ws + off);  off += 262144u;
  signed char*    wqb   = (signed char*)(ws + off);     off += 262144u;
  signed char*    hst   = (signed char*)(ws + off);     off += 131072u;
  float*          cst   = (float*)(ws + off);           off += 524288u;
  float*          bcv   = (float*)(ws + off);           off += 4096u;
  float*          scl   = (float*)(ws + off);

  zero2<<<1, 64, 0, stream>>>(scl);
  absmax_red<<<128, 256, 0, stream>>>(whh, 262144, scl + 0);
  absmax_red<<<64, 256, 0, stream>>>(h0, 131072, scl + 1);
  wperm_cast<<<128, 256, 0, stream>>>(wih, wih_h);
  bias_perm<<<4, 256, 0, stream>>>(bih, bhh, bcv);
  quant_w<<<1024, 256, 0, stream>>>(whh, scl, wqb, 262144);
  state_init<<<512, 256, 0, stream>>>(h0, c0, scl, hst, cst);

  int nchunks = 512 / tc;
  for (int c = 0; c < nchunks; ++c) {
    xgemm<<<4 * tc, 256, 0, stream>>>(x, wih_h, bcv, xgb, c * tc, tclog);
    lstm_chunk<<<256, 512, 0, stream>>>(xgb, wqb, scl, hst, cst, tc, c == 0 ? 1 : 0);
  }
  finalize<<<512, 256, 0, stream>>>(cst, out);
}

// Round 6
// 547.871 us; speedup vs baseline: 3.1858x; 1.0730x over previous
//
#include <hip/hip_runtime.h>
#include <hip/hip_bf16.h>
#include <hip/hip_fp16.h>

// LSTM: B=512, T=512, I=128, H=256, gates G=4H=1024 (PyTorch i,f,g,o order).
// Fused pipeline: per chunk c, ONE launch runs lstm(chunk c) on blocks 0-127
// (R=4 batch rows/block, w_hh i8 in 128 regs/thread, M-rows {0,4,8,12} so the
// elementwise needs NO cross-lane moves) concurrently with xgemm(chunk c+1) on
// blocks 128-255 (into the other xg buffer). Kernel boundaries carry the deps.

typedef __attribute__((ext_vector_type(4))) float f32x4;
typedef __attribute__((ext_vector_type(8))) _Float16 f16x8;
typedef __attribute__((ext_vector_type(4))) unsigned int u32x4;
typedef __attribute__((ext_vector_type(4))) int i32x4;

static __device__ __forceinline__ float h2f(unsigned short u) {
  return (float)__builtin_bit_cast(_Float16, u);
}
static __device__ __forceinline__ unsigned short f2h(float f) {
  return __builtin_bit_cast(unsigned short, (_Float16)f);
}
static __device__ __forceinline__ float fast_sigmoid(float x) {
  return __builtin_amdgcn_rcpf(1.0f + __builtin_amdgcn_exp2f(-1.44269504f * x));
}
static __device__ __forceinline__ float fast_tanh(float x) {
  return 1.0f - 2.0f * __builtin_amdgcn_rcpf(1.0f + __builtin_amdgcn_exp2f(2.88539008f * x));
}

// ---------------------------------------------------------------- small utils
__global__ void zero2(float* p) { if (threadIdx.x < 2) p[threadIdx.x] = 0.f; }

__global__ void absmax_red(const float* __restrict__ src, int n, float* __restrict__ out) {
  __shared__ float s[256];
  float m = 0.f;
  for (int i = blockIdx.x * 256 + threadIdx.x; i < n; i += gridDim.x * 256)
    m = fmaxf(m, fabsf(src[i]));
  s[threadIdx.x] = m; __syncthreads();
  for (int w = 128; w > 0; w >>= 1) {
    if (threadIdx.x < w) s[threadIdx.x] = fmaxf(s[threadIdx.x], s[threadIdx.x + w]);
    __syncthreads();
  }
  if (threadIdx.x == 0) atomicMax((int*)out, __float_as_int(s[0]));
}

__global__ void quant_w(const float* __restrict__ w, const float* __restrict__ scales,
                        signed char* __restrict__ wq, int n) {
  int i = blockIdx.x * 256 + threadIdx.x;
  if (i < n) {
    float inv = 127.0f / scales[0];
    int q = (int)rintf(w[i] * inv);
    q = max(-127, min(127, q));
    wq[i] = (signed char)q;
  }
}

// w_ih cast with gate-row interleave: dst row q <- src row (q&3)*256 + (q>>2)
__global__ void wperm_cast(const float* __restrict__ w, unsigned short* __restrict__ dst) {
  int i = (blockIdx.x * 256 + threadIdx.x) * 4;  // over 131072
  if (i < 131072) {
    int q = i >> 7, k = i & 127;
    int p = (q & 3) * 256 + (q >> 2);
    f32x4 v = *(const f32x4*)(w + p * 128 + k);
    ushort4 pk;
    pk.x = f2h(v[0]); pk.y = f2h(v[1]); pk.z = f2h(v[2]); pk.w = f2h(v[3]);
    *(ushort4*)(dst + i) = pk;
  }
}

__global__ void bias_perm(const float* __restrict__ bi, const float* __restrict__ bh,
                          float* __restrict__ bc) {
  int q = blockIdx.x * 256 + threadIdx.x;  // 1024
  int p = (q & 3) * 256 + (q >> 2);
  bc[q] = bi[p] + bh[p];
}

__global__ void state_init(const float* __restrict__ h0, const float* __restrict__ c0,
                           const float* __restrict__ scales,
                           signed char* __restrict__ hst, float* __restrict__ cst) {
  int i = blockIdx.x * 256 + threadIdx.x;  // grid 512 -> 131072
  float inv = 127.0f / scales[1];
  int q = (int)rintf(h0[i] * inv);
  q = max(-127, min(127, q));
  hst[i] = (signed char)q;
  cst[i] = c0[i];
}

// ---------------------------------------------------------------- prologue gemm
// 256 threads, 128-row tile; output col IS interleaved index q = col*4+gate.
__global__ __launch_bounds__(256) void xgemm(
    const float* __restrict__ x, const unsigned short* __restrict__ wih,
    const float* __restrict__ bconv,
    unsigned short* __restrict__ xg, int t0, int tclog) {
  __shared__ unsigned short Ash[128 * 128];
  __shared__ unsigned short Bsh[128 * 128];

  const int tid  = threadIdx.x;
  const int lane = tid & 63;
  const int wv   = tid >> 6;
  const int c16  = lane & 15;
  const int gq   = lane >> 4;
  const long m0  = (long)blockIdx.x * 128;
  const int tcm  = (1 << tclog) - 1;

#pragma unroll
  for (int i = 0; i < 16; ++i) {
    int fidx = (i * 256 + tid) * 4;
    int row = fidx >> 7, k = fidx & 127;
    long cr = m0 + row;
    long b  = cr >> tclog;
    long tl = cr & tcm;
    f32x4 v = *(const f32x4*)(x + ((size_t)b * 512 + t0 + tl) * 128 + k);
    ushort4 pk;
    pk.x = f2h(v[0]); pk.y = f2h(v[1]); pk.z = f2h(v[2]); pk.w = f2h(v[3]);
    int byte = (row * 256 + k * 2) ^ ((row & 7) << 4);
    *(ushort4*)((char*)Ash + byte) = pk;
  }

  const int mh = (wv >> 1) * 64;
  const int nh = (wv & 1) * 64;

  for (int nc = 0; nc < 8; ++nc) {
    __syncthreads();
    {
      const char* wb = (const char*)(wih + nc * 128 * 128);
#pragma unroll
      for (int i = 0; i < 8; ++i) {
        int idx16 = i * 256 + tid;
        int row = idx16 >> 4, ch = idx16 & 15;
        int srcoff = row * 256 + ((ch * 16) ^ ((row & 7) << 4));
        u32x4 v = *(const u32x4*)(wb + srcoff);
        *(u32x4*)((char*)Bsh + idx16 * 16) = v;
      }
    }
    __syncthreads();

    float bias_v[4];
#pragma unroll
    for (int nt = 0; nt < 4; ++nt)
      bias_v[nt] = bconv[nc * 128 + nh + nt * 16 + c16];

    f16x8 af[4][4], bfr[4][4];
#pragma unroll
    for (int sm = 0; sm < 4; ++sm)
#pragma unroll
      for (int kt = 0; kt < 4; ++kt) {
        int m = mh + sm * 16 + c16;
        int byte = (m * 256 + (kt * 32 + gq * 8) * 2) ^ ((m & 7) << 4);
        af[sm][kt] = __builtin_bit_cast(f16x8, *(const u32x4*)((const char*)Ash + byte));
      }
#pragma unroll
    for (int nt = 0; nt < 4; ++nt)
#pragma unroll
      for (int kt = 0; kt < 4; ++kt) {
        int n = nh + nt * 16 + c16;
        int byte = (n * 256 + (kt * 32 + gq * 8) * 2) ^ ((n & 7) << 4);
        bfr[nt][kt] = __builtin_bit_cast(f16x8, *(const u32x4*)((const char*)Bsh + byte));
      }

    f32x4 acc[4][4];
#pragma unroll
    for (int sm = 0; sm < 4; ++sm)
#pragma unroll
      for (int nt = 0; nt < 4; ++nt) { f32x4 z = {0.f, 0.f, 0.f, 0.f}; acc[sm][nt] = z; }
#pragma unroll
    for (int sm = 0; sm < 4; ++sm)
#pragma unroll
      for (int nt = 0; nt < 4; ++nt)
#pragma unroll
        for (int kt = 0; kt < 4; ++kt)
          acc[sm][nt] = __builtin_amdgcn_mfma_f32_16x16x32_f16(af[sm][kt], bfr[nt][kt], acc[sm][nt], 0, 0, 0);

#pragma unroll
    for (int sm = 0; sm < 4; ++sm)
#pragma unroll
      for (int nt = 0; nt < 4; ++nt) {
        long row = m0 + mh + sm * 16 + gq * 4;
        int gcol = nc * 128 + nh + nt * 16 + c16;
#pragma unroll
        for (int r = 0; r < 4; ++r)
          xg[(size_t)(row + r) * 1024 + gcol] = f2h(acc[sm][nt][r] + bias_v[nt]);
      }
  }
}

// ---------------------------------------------------------------- fused kernel
// blocks 0-127: lstm chunk c (4 batch rows each). blocks 128-255: xgemm c+1.
__global__ __launch_bounds__(512, 2) void fused_chunk(
    const unsigned short* __restrict__ xgc, const signed char* __restrict__ wq,
    const float* __restrict__ scales, signed char* __restrict__ hst,
    float* __restrict__ cst, float* __restrict__ out, int Tc, int first, int last,
    const float* __restrict__ x, const unsigned short* __restrict__ wih,
    const float* __restrict__ bconv, unsigned short* __restrict__ xgn,
    int t0n, int tclog, int do_x) {
  __shared__ char smem[65536];

  const int tid  = threadIdx.x;
  const int lane = tid & 63;
  const int wv   = tid >> 6;      // 0..7
  const int c16  = lane & 15;
  const int gq   = lane >> 4;     // 0..3

  if (blockIdx.x < 128) {
    // ------------------------------ LSTM: 4 batch rows, M-rows {0,4,8,12}
    signed char (*hb)[1280] = (signed char (*)[1280])smem;  // [buf][4 rows x 320B]
    const int b0 = blockIdx.x * 4;

    // weights: n = (nt>>1)*256 + wv*32 + (nt&1)*16 + c16 ; k = kt*64 + gq*16
    i32x4 wf[8][4];
#pragma unroll
    for (int nt = 0; nt < 8; ++nt)
#pragma unroll
      for (int kt = 0; kt < 4; ++kt) {
        int n = (nt >> 1) * 256 + wv * 32 + (nt & 1) * 16 + c16;
        wf[nt][kt] = *(const i32x4*)(wq + n * 256 + kt * 64 + gq * 16);
      }

    // init hb[0]: rows 0..3 (stride 320B), cols 0..255
    for (int i = tid; i < 1024; i += 512) {
      int row = i >> 8, cc = i & 255;
      hb[0][row * 320 + cc] = hst[(b0 + row) * 256 + cc];
    }

    const int col = wv * 32 + c16;     // output cols: col and col+16; row = gq
    float cv0 = cst[(b0 + gq) * 256 + col];
    float cv1 = cst[(b0 + gq) * 256 + col + 16];

    const float sw   = scales[0] * (1.0f / 127.0f);
    const float facR = sw * (1.0f / 127.0f);
    const float fac0 = first ? sw * (scales[1] * (1.0f / 127.0f)) : facR;

    const char* pxp = (const char*)(xgc + ((size_t)(b0 + gq) * Tc) * 1024 + col * 4);
    ushort4 px0 = *(const ushort4*)pxp;
    ushort4 px1 = *(const ushort4*)(pxp + 128);
    pxp += 2048;

    const bool mrow = (c16 & 3) == 0;  // A-lanes: M-rows 0,4,8,12
    const int  hrow = c16 >> 2;
    i32x4 af[4];
#pragma unroll
    for (int kt = 0; kt < 4; ++kt) { i32x4 z = {0, 0, 0, 0}; af[kt] = z; }
    const i32x4 zacc = {0, 0, 0, 0};
    int q0 = 0, q1 = 0;

    __syncthreads();

    for (int tt = 0; tt < Tc; ++tt) {
      const int cur = tt & 1;

      // prefetch next step's xg (last iter reads into adjacent ws region; unused)
      ushort4 pn0 = *(const ushort4*)pxp;
      ushort4 pn1 = *(const ushort4*)(pxp + 128);
      pxp += 2048;

      if (mrow) {
        const signed char* hp = &hb[cur][hrow * 320 + gq * 16];
        af[0] = *(const i32x4*)(hp);
        af[1] = *(const i32x4*)(hp + 64);
        af[2] = *(const i32x4*)(hp + 128);
        af[3] = *(const i32x4*)(hp + 192);
      }

      i32x4 acc[8];
#pragma unroll
      for (int nt = 0; nt < 8; ++nt)
        acc[nt] = __builtin_amdgcn_mfma_i32_16x16x64_i8(af[0], wf[nt][0], zacc, 0, 0, 0);
#pragma unroll
      for (int kt = 1; kt < 4; ++kt)
#pragma unroll
        for (int nt = 0; nt < 8; ++nt)
          acc[nt] = __builtin_amdgcn_mfma_i32_16x16x64_i8(af[kt], wf[nt][kt], acc[nt], 0, 0, 0);

      const float fac = (tt == 0) ? fac0 : facR;

      // D row = gq*4 + reg -> reg 0 of every gq group is a real batch row (gq).
      // parity p=0 (acc even) -> col; p=1 (acc odd) -> col+16. No cross-lane.
      {
        float gi = __builtin_fmaf((float)acc[0][0], fac, h2f(px0.x));
        float gf = __builtin_fmaf((float)acc[2][0], fac, h2f(px0.y));
        float gg = __builtin_fmaf((float)acc[4][0], fac, h2f(px0.z));
        float go = __builtin_fmaf((float)acc[6][0], fac, h2f(px0.w));
        cv0 = fast_sigmoid(gf) * cv0 + fast_sigmoid(gi) * fast_tanh(gg);
        float hn = fast_sigmoid(go) * fast_tanh(cv0);
        q0 = (int)rintf(hn * 127.0f);
        hb[cur ^ 1][gq * 320 + col] = (signed char)q0;
      }
      {
        float gi = __builtin_fmaf((float)acc[1][0], fac, h2f(px1.x));
        float gf = __builtin_fmaf((float)acc[3][0], fac, h2f(px1.y));
        float gg = __builtin_fmaf((float)acc[5][0], fac, h2f(px1.z));
        float go = __builtin_fmaf((float)acc[7][0], fac, h2f(px1.w));
        cv1 = fast_sigmoid(gf) * cv1 + fast_sigmoid(gi) * fast_tanh(gg);
        float hn = fast_sigmoid(go) * fast_tanh(cv1);
        q1 = (int)rintf(hn * 127.0f);
        hb[cur ^ 1][gq * 320 + col + 16] = (signed char)q1;
      }

      px0 = pn0; px1 = pn1;
      __syncthreads();
    }

    cst[(b0 + gq) * 256 + col]      = cv0;
    cst[(b0 + gq) * 256 + col + 16] = cv1;
    hst[(b0 + gq) * 256 + col]      = (signed char)q0;
    hst[(b0 + gq) * 256 + col + 16] = (signed char)q1;
    if (last) {
      out[(b0 + gq) * 256 + col]      = cv0;
      out[(b0 + gq) * 256 + col + 16] = cv1;
    }
  } else if (do_x) {
    // ------------------------------ XGEMM for chunk c+1 (512 threads/tile)
    unsigned short* Ash = (unsigned short*)smem;            // 128x128 f16
    unsigned short* Bsh = (unsigned short*)(smem + 32768);  // 128x128 f16
    const int tcm    = (1 << tclog) - 1;
    const int ntiles = Tc << 2;          // (512*Tc)/128
    const int wm = wv >> 2, wn = wv & 3; // 2x4 wave grid
    const int mh = wm * 64, nh = wn * 32;

    for (int rt = (int)blockIdx.x - 128; rt < ntiles; rt += 128) {
      const long m0 = (long)rt * 128;
      __syncthreads();  // previous tile's readers done before re-staging

      // stage A: 128 rows x 128 k, f32 -> f16, swizzled
#pragma unroll
      for (int i = 0; i < 8; ++i) {
        int fidx = (i * 512 + tid) * 4;
        int row = fidx >> 7, k = fidx & 127;
        long cr = m0 + row;
        long b  = cr >> tclog;
        long tl = cr & tcm;
        f32x4 v = *(const f32x4*)(x + ((size_t)b * 512 + t0n + tl) * 128 + k);
        ushort4 pk;
        pk.x = f2h(v[0]); pk.y = f2h(v[1]); pk.z = f2h(v[2]); pk.w = f2h(v[3]);
        int byte = (row * 256 + k * 2) ^ ((row & 7) << 4);
        *(ushort4*)((char*)Ash + byte) = pk;
      }

      for (int nc = 0; nc < 8; ++nc) {
        __syncthreads();
        {
          const char* wb = (const char*)(wih + nc * 128 * 128);
#pragma unroll
          for (int i = 0; i < 4; ++i) {
            int idx16 = i * 512 + tid;
            int row = idx16 >> 4, ch = idx16 & 15;
            int srcoff = row * 256 + ((ch * 16) ^ ((row & 7) << 4));
            u32x4 v = *(const u32x4*)(wb + srcoff);
            *(u32x4*)((char*)Bsh + idx16 * 16) = v;
          }
        }
        __syncthreads();

        float bias_v[2];
#pragma unroll
        for (int nt = 0; nt < 2; ++nt)
          bias_v[nt] = bconv[nc * 128 + nh + nt * 16 + c16];

        f16x8 af[4][4], bfr[2][4];
#pragma unroll
        for (int sm = 0; sm < 4; ++sm)
#pragma unroll
          for (int kt = 0; kt < 4; ++kt) {
            int m = mh + sm * 16 + c16;
            int byte = (m * 256 + (kt * 32 + gq * 8) * 2) ^ ((m & 7) << 4);
            af[sm][kt] = __builtin_bit_cast(f16x8, *(const u32x4*)((const char*)Ash + byte));
          }
#pragma unroll
        for (int nt = 0; nt < 2; ++nt)
#pragma unroll
          for (int kt = 0; kt < 4; ++kt) {
            int n = nh + nt * 16 + c16;
            int byte = (n * 256 + (kt * 32 + gq * 8) * 2) ^ ((n & 7) << 4);
            bfr[nt][kt] = __builtin_bit_cast(f16x8, *(const u32x4*)((const char*)Bsh + byte));
          }

        f32x4 acc[4][2];
#pragma unroll
        for (int sm = 0; sm < 4; ++sm)
#pragma unroll
          for (int nt = 0; nt < 2; ++nt) { f32x4 z = {0.f, 0.f, 0.f, 0.f}; acc[sm][nt] = z; }
#pragma unroll
        for (int sm = 0; sm < 4; ++sm)
#pragma unroll
          for (int nt = 0; nt < 2; ++nt)
#pragma unroll
            for (int kt = 0; kt < 4; ++kt)
              acc[sm][nt] = __builtin_amdgcn_mfma_f32_16x16x32_f16(af[sm][kt], bfr[nt][kt], acc[sm][nt], 0, 0, 0);

#pragma unroll
        for (int sm = 0; sm < 4; ++sm)
#pragma unroll
          for (int nt = 0; nt < 2; ++nt) {
            long row = m0 + mh + sm * 16 + gq * 4;
            int gcol = nc * 128 + nh + nt * 16 + c16;
#pragma unroll
            for (int r = 0; r < 4; ++r)
              xgn[(size_t)(row + r) * 1024 + gcol] = f2h(acc[sm][nt][r] + bias_v[nt]);
          }
      }
    }
  }
}

// ---------------------------------------------------------------- launch
extern "C" void kernel_launch(void* const* d_in, const int* in_sizes, int n_in,
                              void* d_out, int out_size, void* d_ws, size_t ws_size,
                              hipStream_t stream) {
  const float* x   = (const float*)d_in[0];
  const float* h0  = (const float*)d_in[1];
  const float* c0  = (const float*)d_in[2];
  const float* wih = (const float*)d_in[3];
  const float* whh = (const float*)d_in[4];
  const float* bih = (const float*)d_in[5];
  const float* bhh = (const float*)d_in[6];
  float* out = (float*)d_out;

  const size_t fixed = 262144u /*wih f16*/ + 262144u /*wq*/ + 131072u /*hst*/
                     + 524288u /*cst*/ + 4096u /*bconv*/ + 256u /*scales*/;
  int tc = 512;
  while (tc > 4 && 2u * (size_t)512 * tc * 2048 + fixed > ws_size) tc >>= 1;
  int tclog = 31 - __builtin_clz((unsigned)tc);
  size_t bufsz = (size_t)512 * tc * 2048;

  char* ws = (char*)d_ws;
  unsigned short* xgb0  = (unsigned short*)ws;
  unsigned short* xgb1  = (unsigned short*)(ws + bufsz);
  size_t off = 2u * bufsz;
  unsigned short* wih_h = (unsigned short*)(ws + off);  off += 262144u;
  signed char*    wqb   = (signed char*)(ws + off);     off += 262144u;
  signed char*    hst   = (signed char*)(ws + off);     off += 131072u;
  float*          cst   = (float*)(ws + off);           off += 524288u;
  float*          bcv   = (float*)(ws + off);           off += 4096u;
  float*          scl   = (float*)(ws + off);

  zero2<<<1, 64, 0, stream>>>(scl);
  absmax_red<<<128, 256, 0, stream>>>(whh, 262144, scl + 0);
  absmax_red<<<64, 256, 0, stream>>>(h0, 131072, scl + 1);
  wperm_cast<<<128, 256, 0, stream>>>(wih, wih_h);
  bias_perm<<<4, 256, 0, stream>>>(bih, bhh, bcv);
  quant_w<<<1024, 256, 0, stream>>>(whh, scl, wqb, 262144);
  state_init<<<512, 256, 0, stream>>>(h0, c0, scl, hst, cst);

  // prologue: xgemm for chunk 0 (full chip)
  xgemm<<<4 * tc, 256, 0, stream>>>(x, wih_h, bcv, xgb0, 0, tclog);

  int NC = 512 / tc;
  for (int c = 0; c < NC; ++c) {
    unsigned short* cur = (c & 1) ? xgb1 : xgb0;
    unsigned short* nxt = (c & 1) ? xgb0 : xgb1;
    int do_x = (c + 1 < NC) ? 1 : 0;
    fused_chunk<<<256, 512, 0, stream>>>(
        cur, wqb, scl, hst, cst, out, tc, (c == 0) ? 1 : 0, (c == NC - 1) ? 1 : 0,
        x, wih_h, bcv, nxt, (c + 1) * tc, tclog, do_x);
  }
}